// Round 1
// baseline (616.821 us; speedup 1.0000x reference)
//
#include <hip/hip_runtime.h>
#include <hip/hip_bf16.h>
#include <stdint.h>

// BitNet b1.58 linear: out[M,N] = x[M,K] @ (ternary(W)*scale)[N,K]^T + bias[N]
// M=8192, N=4096, K=4096.
//
// R2 -> R3: GEMM rewritten from 128x128 2-barrier structure (ceiling ~1090 TF
// here) to the 256x256 8-phase deep-pipelined template (T3+T4+T5+T1):
//  - BK=64, 8 waves (2Mx4N), per-wave 128x64 output, 128 KiB LDS dbuf
//  - 8 phases / 2 K-tiles; counted s_waitcnt vmcnt(4) only at phases 4 & 8
//    (loads stay in flight across barriers; never drain to 0 in main loop)
//  - raw s_barrier pairs per phase; s_setprio(1) around MFMA clusters
//  - XOR chunk swizzle (phys = chunk ^ (row&7)) carried over from R2
//  - bijective XCD swizzle on blockIdx (nwg=512, 512%8==0)
// Prepass kernels unchanged.

typedef __bf16 bf16x8 __attribute__((ext_vector_type(8)));
typedef float f32x4 __attribute__((ext_vector_type(4)));
typedef unsigned short u16x8 __attribute__((ext_vector_type(8)));

__device__ __forceinline__ unsigned short f2bf_rne(float f) {
  union { float f; unsigned int u; } v; v.f = f;
  unsigned int u = v.u;
  u += 0x7FFFu + ((u >> 16) & 1u);
  return (unsigned short)(u >> 16);
}

// ---------------------------------------------------------------- reduction
__global__ void absum_kernel(const float4* __restrict__ w, int n4,
                             double* __restrict__ out) {
  float s = 0.f;
  for (int i = blockIdx.x * blockDim.x + threadIdx.x; i < n4;
       i += gridDim.x * blockDim.x) {
    float4 v = w[i];
    s += fabsf(v.x) + fabsf(v.y) + fabsf(v.z) + fabsf(v.w);
  }
#pragma unroll
  for (int off = 32; off > 0; off >>= 1) s += __shfl_down(s, off);
  __shared__ float partial[4];
  if ((threadIdx.x & 63) == 0) partial[threadIdx.x >> 6] = s;
  __syncthreads();
  if (threadIdx.x == 0)
    atomicAdd(out, (double)(partial[0] + partial[1] + partial[2] + partial[3]));
}

// ---------------------------------------------------------------- quantize W
__global__ void quant_kernel(const float4* __restrict__ w, int n8,
                             const double* __restrict__ sum, double inv_cnt,
                             u16x8* __restrict__ q) {
  float scale = (float)fmin(fmax(sum[0] * inv_cnt, 1e-5), 1000.0);
  const float T = 2.0f / 3.0f;
  for (int i = blockIdx.x * blockDim.x + threadIdx.x; i < n8;
       i += gridDim.x * blockDim.x) {
    float4 a = w[2 * i], b = w[2 * i + 1];
    float f[8] = {a.x, a.y, a.z, a.w, b.x, b.y, b.z, b.w};
    u16x8 o;
#pragma unroll
    for (int j = 0; j < 8; ++j) {
      float n = f[j] / scale;
      o[j] = (n > T) ? 0x3F80u : ((n < -T) ? 0xBF80u : 0u);
    }
    q[i] = o;
  }
}

// ---------------------------------------------------------------- x -> bf16
__global__ void xcvt_kernel(const float4* __restrict__ x, int n8,
                            u16x8* __restrict__ xb) {
  for (int i = blockIdx.x * blockDim.x + threadIdx.x; i < n8;
       i += gridDim.x * blockDim.x) {
    float4 a = x[2 * i], b = x[2 * i + 1];
    float f[8] = {a.x, a.y, a.z, a.w, b.x, b.y, b.z, b.w};
    u16x8 o;
#pragma unroll
    for (int j = 0; j < 8; ++j) o[j] = f2bf_rne(f[j]);
    xb[i] = o;
  }
}

// ---------------------------------------------------------------- GEMM
// 256x256 tile, BK=64, 512 threads (8 waves: wm = w>>2 in {0,1}, wn = w&3).
// LDS: As/Bs[2 dbuf][2 half][128 rows][64 cols] bf16 = 64 KiB each.
// Tile t -> buf (t&1): every iteration reads buf0 (tile 2i) in ph1-4 and
// buf1 (tile 2i+1) in ph5-8. Fixed roles, no parity flip.

#define BKT 64

#define FENCE() asm volatile("" ::: "memory")
#define BAR() __builtin_amdgcn_s_barrier()
#define WAIT_LGKM0() asm volatile("s_waitcnt lgkmcnt(0)" ::: "memory")
#define WAIT_VM4() asm volatile("s_waitcnt vmcnt(4)" ::: "memory")

__global__ __launch_bounds__(512, 2)
void gemm_kernel(const ushort* __restrict__ xb,   // [M,K] bf16 bits
                 const ushort* __restrict__ qb,   // [N,K] bf16 bits
                 const float* __restrict__ bias,  // [N]
                 const double* __restrict__ sum,
                 float* __restrict__ out,         // [M,N]
                 int M, int N, int K, double inv_cnt) {
  __shared__ __align__(16) ushort As[2][2][128][64];
  __shared__ __align__(16) ushort Bs[2][2][128][64];

  const int t = threadIdx.x;
  const int w = t >> 6;
  const int lane = t & 63;
  const int wm = w >> 2;  // 0..1, wave's 128-row slab
  const int wn = w & 3;   // 0..3, wave's 64-col slab
  const int lm = lane & 15;
  const int lk = lane >> 4;

  // bijective XCD swizzle (nwg % 8 == 0)
  const int nbx = N >> 8;
  const int cpx = gridDim.x >> 3;
  const int id = blockIdx.x;
  const int swz = (id & 7) * cpx + (id >> 3);
  const int bx = swz % nbx;
  const int by = swz / nbx;
  const int m0 = by << 8;
  const int n0 = bx << 8;

  // staging geometry: per half-tile (128 rows x 64 cols bf16 = 16 KiB),
  // 2 global_load_lds x 16 B per thread. Load s: wave w covers rows
  // [s*64 + w*8, +8). LDS dest is linear (wave-uniform base + lane*16B);
  // the XOR swizzle is applied on the GLOBAL source chunk: phys chunk
  // (l&7) of row r holds logical chunk (l&7)^(r&7).
  const int srow = lane >> 3;              // 0..7
  const int schunk = (lane & 7) ^ srow;    // pre-swizzled source chunk
  const ushort* aSrc = xb + (size_t)(m0 + w * 8 + srow) * K + schunk * 8;
  const ushort* bSrc = qb + (size_t)(n0 + w * 8 + srow) * K + schunk * 8;

#define STAGE_A(BUF, H, KT)                                                    \
  do {                                                                         \
    _Pragma("unroll") for (int s_ = 0; s_ < 2; ++s_) {                         \
      __builtin_amdgcn_global_load_lds(                                        \
          (const __attribute__((address_space(1))) void*)(                     \
              aSrc + (size_t)((H) * 128 + s_ * 64) * K + (KT) * BKT),          \
          (__attribute__((address_space(3))) void*)(                           \
              &As[BUF][H][s_ * 64 + w * 8][0]),                                \
          16, 0, 0);                                                           \
    }                                                                          \
  } while (0)

#define STAGE_B(BUF, H, KT)                                                    \
  do {                                                                         \
    _Pragma("unroll") for (int s_ = 0; s_ < 2; ++s_) {                         \
      __builtin_amdgcn_global_load_lds(                                        \
          (const __attribute__((address_space(1))) void*)(                     \
              bSrc + (size_t)((H) * 128 + s_ * 64) * K + (KT) * BKT),          \
          (__attribute__((address_space(3))) void*)(                           \
              &Bs[BUF][H][s_ * 64 + w * 8][0]),                                \
          16, 0, 0);                                                           \
    }                                                                          \
  } while (0)

  // fragment reads: logical k-chunk c = ks*4+lk lives at phys chunk c^(r&7),
  // r&7 == lm&7 (row bases are multiples of 16).
#define RD_A(BUF, MH)                                                          \
  _Pragma("unroll") for (int mq = 0; mq < 4; ++mq)                             \
  _Pragma("unroll") for (int ks = 0; ks < 2; ++ks)                             \
      af[mq][ks] = *(const bf16x8*)&As[BUF][wm][(MH) * 64 + mq * 16 + lm]      \
                                      [((ks * 4 + lk) ^ (lm & 7)) * 8];

#define RD_B(BUF, NF0)                                                         \
  _Pragma("unroll") for (int nf = (NF0); nf < (NF0) + 2; ++nf)                 \
  _Pragma("unroll") for (int ks = 0; ks < 2; ++ks)                             \
      bf[nf][ks] =                                                             \
          *(const bf16x8*)&Bs[BUF][wn >> 1][(wn & 1) * 64 + nf * 16 + lm]      \
                              [((ks * 4 + lk) ^ (lm & 7)) * 8];

#define MFMA_Q(MH, NB)                                                         \
  _Pragma("unroll") for (int mq = 0; mq < 4; ++mq)                             \
  _Pragma("unroll") for (int nq = 0; nq < 2; ++nq)                             \
  _Pragma("unroll") for (int ks = 0; ks < 2; ++ks)                             \
      acc[(MH) * 4 + mq][(NB) + nq] =                                          \
          __builtin_amdgcn_mfma_f32_16x16x32_bf16(                             \
              af[mq][ks], bf[(NB) + nq][ks], acc[(MH) * 4 + mq][(NB) + nq],    \
              0, 0, 0);

  f32x4 acc[8][4] = {};
  bf16x8 af[4][2];
  bf16x8 bf[4][2];

  // prologue: tile0 (A+B) -> buf0, tile1 B -> buf1 (tile1 A staged in ph1-2)
  STAGE_A(0, 0, 0); STAGE_A(0, 1, 0);
  STAGE_B(0, 0, 0); STAGE_B(0, 1, 0);
  STAGE_B(1, 0, 1); STAGE_B(1, 1, 1);
  WAIT_VM4();  // 12 loads out; allow newest 4 (tile1 B) in flight, tile0 done
  FENCE(); BAR(); FENCE();

  const int NT = K / BKT;  // 64
  for (int i = 0; i < NT / 2; ++i) {
    const int kt1 = 2 * i + 1;                                // always valid
    const int kt2 = (2 * i + 2 < NT) ? (2 * i + 2) : (NT - 1);  // clamp tail
    const int kt3 = (2 * i + 3 < NT) ? (2 * i + 3) : (NT - 1);

    // ---- phase 1: read A-lo + B-lo (buf0); stage A0(2i+1)->buf1
    RD_A(0, 0); RD_B(0, 0);
    STAGE_A(1, 0, kt1);
    FENCE(); BAR(); WAIT_LGKM0();
    __builtin_amdgcn_s_setprio(1); MFMA_Q(0, 0); __builtin_amdgcn_s_setprio(0);
    FENCE(); BAR();

    // ---- phase 2: read B-hi; stage A1(2i+1)->buf1
    RD_B(0, 2);
    STAGE_A(1, 1, kt1);
    FENCE(); BAR(); WAIT_LGKM0();
    __builtin_amdgcn_s_setprio(1); MFMA_Q(0, 2); __builtin_amdgcn_s_setprio(0);
    FENCE(); BAR();

    // ---- phase 3: read A-hi; stage B0(2i+2)->buf0 (B slots free since ph3)
    RD_A(0, 1);
    STAGE_B(0, 0, kt2);
    FENCE(); BAR(); WAIT_LGKM0();
    __builtin_amdgcn_s_setprio(1); MFMA_Q(1, 2); __builtin_amdgcn_s_setprio(0);
    FENCE(); BAR();

    // ---- phase 4: no reads; stage B1(2i+2)->buf0; vmcnt(4) -> tile 2i+1 done
    STAGE_B(0, 1, kt2);
    FENCE(); BAR();
    __builtin_amdgcn_s_setprio(1); MFMA_Q(1, 0); __builtin_amdgcn_s_setprio(0);
    WAIT_VM4();
    FENCE(); BAR();

    // ---- phase 5: read A-lo + B-lo (buf1); stage A0(2i+2)->buf0
    RD_A(1, 0); RD_B(1, 0);
    STAGE_A(0, 0, kt2);
    FENCE(); BAR(); WAIT_LGKM0();
    __builtin_amdgcn_s_setprio(1); MFMA_Q(0, 0); __builtin_amdgcn_s_setprio(0);
    FENCE(); BAR();

    // ---- phase 6: read B-hi; stage A1(2i+2)->buf0
    RD_B(1, 2);
    STAGE_A(0, 1, kt2);
    FENCE(); BAR(); WAIT_LGKM0();
    __builtin_amdgcn_s_setprio(1); MFMA_Q(0, 2); __builtin_amdgcn_s_setprio(0);
    FENCE(); BAR();

    // ---- phase 7: read A-hi; stage B0(2i+3)->buf1
    RD_A(1, 1);
    STAGE_B(1, 0, kt3);
    FENCE(); BAR(); WAIT_LGKM0();
    __builtin_amdgcn_s_setprio(1); MFMA_Q(1, 2); __builtin_amdgcn_s_setprio(0);
    FENCE(); BAR();

    // ---- phase 8: no reads; stage B1(2i+3)->buf1; vmcnt(4) -> tile 2i+2 done
    STAGE_B(1, 1, kt3);
    FENCE(); BAR();
    __builtin_amdgcn_s_setprio(1); MFMA_Q(1, 0); __builtin_amdgcn_s_setprio(0);
    WAIT_VM4();
    FENCE(); BAR();
  }

  float scale = (float)fmin(fmax(sum[0] * inv_cnt, 1e-5), 1000.0);

  // C/D layout (m89-verified): col = lane&15, row = (lane>>4)*4 + reg
#pragma unroll
  for (int nf = 0; nf < 4; ++nf) {
    const int col = n0 + wn * 64 + nf * 16 + lm;
    const float bv = bias[col];
#pragma unroll
    for (int mf = 0; mf < 8; ++mf) {
      const int row = m0 + wm * 128 + mf * 16 + lk * 4;
      float* op = out + (size_t)row * N + col;
#pragma unroll
      for (int r = 0; r < 4; ++r)
        op[(size_t)r * N] = acc[mf][nf][r] * scale + bv;
    }
  }
}

// ---------------------------------------------------------------- launch
extern "C" void kernel_launch(void* const* d_in, const int* in_sizes, int n_in,
                              void* d_out, int out_size, void* d_ws,
                              size_t ws_size, hipStream_t stream) {
  const float* x = (const float*)d_in[0];
  const float* w = (const float*)d_in[1];
  const float* bias = (const float*)d_in[2];
  float* out = (float*)d_out;

  const int DOUT = in_sizes[2];        // 4096
  const int DIN = in_sizes[1] / DOUT;  // 4096
  const int M = in_sizes[0] / DIN;     // 8192
  const int N = DOUT, K = DIN;

  char* ws = (char*)d_ws;
  double* sum = (double*)ws;                                   // 8 B
  ushort* xb = (ushort*)(ws + 256);                            // M*K*2 B
  ushort* qb = (ushort*)(ws + 256 + (size_t)M * K * 2);        // N*K*2 B

  const double inv_cnt = 1.0 / ((double)N * (double)K);

  hipMemsetAsync(d_ws, 0, 8, stream);

  const int wn4 = (N * K) / 4;
  const int wn8 = (N * K) / 8;
  absum_kernel<<<2048, 256, 0, stream>>>((const float4*)w, wn4, sum);
  quant_kernel<<<4096, 256, 0, stream>>>((const float4*)w, wn8, sum, inv_cnt,
                                         (u16x8*)qb);
  const int xn8 = (M * K) / 8;
  xcvt_kernel<<<8192, 256, 0, stream>>>((const float4*)x, xn8, (u16x8*)xb);

  const int nwg = (M >> 8) * (N >> 8);  // 32*16 = 512, divisible by 8
  gemm_kernel<<<dim3(nwg), 512, 0, stream>>>(xb, qb, bias, sum, out, M, N, K,
                                             inv_cnt);
}

// Round 3
// 587.112 us; speedup vs baseline: 1.0506x; 1.0506x over previous
//
#include <hip/hip_runtime.h>
#include <hip/hip_bf16.h>
#include <stdint.h>

// BitNet b1.58 linear: out[M,N] = x[M,K] @ (ternary(W)*scale)[N,K]^T + bias[N]
// M=8192, N=4096, K=4096.
//
// R5 == R4 resubmit (R4 bench was an infra failure: "container failed twice",
// no counters). Theory under test, vs R3's measured 333.8 us / MfmaUtil 35%:
// R3 waited vmcnt(4) with only 2 phases (~310 cyc) between a half-tile's
// stage and its wait -> whole-block stall every K-tile. R4/R5 stage tile
// t+2's B in ph3 (B slots free after ph2), its A in ph4 (free after ph3),
// symmetric ph7/ph8, and wait vmcnt(8): waited-on loads were issued 4 phases
// (~620+ cyc) earlier, covering L2-hit latency. Same geometry otherwise:
// 256x256 tile, BK=64, 8 waves, 128 KiB LDS dbuf, XOR chunk swizzle,
// bijective XCD swizzle, setprio around MFMA clusters.

typedef __bf16 bf16x8 __attribute__((ext_vector_type(8)));
typedef float f32x4 __attribute__((ext_vector_type(4)));
typedef unsigned short u16x8 __attribute__((ext_vector_type(8)));

__device__ __forceinline__ unsigned short f2bf_rne(float f) {
  union { float f; unsigned int u; } v; v.f = f;
  unsigned int u = v.u;
  u += 0x7FFFu + ((u >> 16) & 1u);
  return (unsigned short)(u >> 16);
}

// ---------------------------------------------------------------- reduction
__global__ void absum_kernel(const float4* __restrict__ w, int n4,
                             double* __restrict__ out) {
  float s = 0.f;
  for (int i = blockIdx.x * blockDim.x + threadIdx.x; i < n4;
       i += gridDim.x * blockDim.x) {
    float4 v = w[i];
    s += fabsf(v.x) + fabsf(v.y) + fabsf(v.z) + fabsf(v.w);
  }
#pragma unroll
  for (int off = 32; off > 0; off >>= 1) s += __shfl_down(s, off);
  __shared__ float partial[4];
  if ((threadIdx.x & 63) == 0) partial[threadIdx.x >> 6] = s;
  __syncthreads();
  if (threadIdx.x == 0)
    atomicAdd(out, (double)(partial[0] + partial[1] + partial[2] + partial[3]));
}

// ---------------------------------------------------------------- quantize W
__global__ void quant_kernel(const float4* __restrict__ w, int n8,
                             const double* __restrict__ sum, double inv_cnt,
                             u16x8* __restrict__ q) {
  float scale = (float)fmin(fmax(sum[0] * inv_cnt, 1e-5), 1000.0);
  const float T = 2.0f / 3.0f;
  for (int i = blockIdx.x * blockDim.x + threadIdx.x; i < n8;
       i += gridDim.x * blockDim.x) {
    float4 a = w[2 * i], b = w[2 * i + 1];
    float f[8] = {a.x, a.y, a.z, a.w, b.x, b.y, b.z, b.w};
    u16x8 o;
#pragma unroll
    for (int j = 0; j < 8; ++j) {
      float n = f[j] / scale;
      o[j] = (n > T) ? 0x3F80u : ((n < -T) ? 0xBF80u : 0u);
    }
    q[i] = o;
  }
}

// ---------------------------------------------------------------- x -> bf16
__global__ void xcvt_kernel(const float4* __restrict__ x, int n8,
                            u16x8* __restrict__ xb) {
  for (int i = blockIdx.x * blockDim.x + threadIdx.x; i < n8;
       i += gridDim.x * blockDim.x) {
    float4 a = x[2 * i], b = x[2 * i + 1];
    float f[8] = {a.x, a.y, a.z, a.w, b.x, b.y, b.z, b.w};
    u16x8 o;
#pragma unroll
    for (int j = 0; j < 8; ++j) o[j] = f2bf_rne(f[j]);
    xb[i] = o;
  }
}

// ---------------------------------------------------------------- GEMM
// 256x256 tile, BK=64, 512 threads (8 waves: wm = w>>2 in {0,1}, wn = w&3).
// LDS: As/Bs[2 dbuf][2 half][128 rows][64 cols] bf16 = 64 KiB each.
// Read schedule per K-tile (4 phases): ph1 A-lo+B-lo, ph2 B-hi, ph3 A-hi,
// ph4 none.  => B slots free after ph2, A slots free after ph3.
// Stage schedule: ph3 stages B(t+2), ph4 stages A(t+2) into the buffer just
// consumed; vmcnt(8) at ph4/ph8 keeps exactly the next tile's 8 loads in
// flight -> 4 phases of issue->wait slack.

#define BKT 64

#define FENCE() asm volatile("" ::: "memory")
#define BAR() __builtin_amdgcn_s_barrier()
#define WAIT_LGKM0() asm volatile("s_waitcnt lgkmcnt(0)" ::: "memory")
#define WAIT_VM8() asm volatile("s_waitcnt vmcnt(8)" ::: "memory")

__global__ __launch_bounds__(512, 2)
void gemm_kernel(const ushort* __restrict__ xb,   // [M,K] bf16 bits
                 const ushort* __restrict__ qb,   // [N,K] bf16 bits
                 const float* __restrict__ bias,  // [N]
                 const double* __restrict__ sum,
                 float* __restrict__ out,         // [M,N]
                 int M, int N, int K, double inv_cnt) {
  __shared__ __align__(16) ushort As[2][2][128][64];
  __shared__ __align__(16) ushort Bs[2][2][128][64];

  const int t = threadIdx.x;
  const int w = t >> 6;
  const int lane = t & 63;
  const int wm = w >> 2;  // 0..1, wave's 128-row slab
  const int wn = w & 3;   // 0..3, wave's 64-col slab
  const int lm = lane & 15;
  const int lk = lane >> 4;

  // bijective XCD swizzle (nwg % 8 == 0)
  const int nbx = N >> 8;
  const int cpx = gridDim.x >> 3;
  const int id = blockIdx.x;
  const int swz = (id & 7) * cpx + (id >> 3);
  const int bx = swz % nbx;
  const int by = swz / nbx;
  const int m0 = by << 8;
  const int n0 = bx << 8;

  // staging geometry: per half-tile (128 rows x 64 cols bf16 = 16 KiB),
  // 2 global_load_lds x 16 B per thread. LDS dest is linear (wave-uniform
  // base + lane*16B); XOR swizzle applied on the GLOBAL source chunk:
  // phys chunk (l&7) of row r holds logical chunk (l&7)^(r&7).
  const int srow = lane >> 3;              // 0..7
  const int schunk = (lane & 7) ^ srow;    // pre-swizzled source chunk
  const ushort* aSrc = xb + (size_t)(m0 + w * 8 + srow) * K + schunk * 8;
  const ushort* bSrc = qb + (size_t)(n0 + w * 8 + srow) * K + schunk * 8;

#define STAGE_A(BUF, H, KT)                                                    \
  do {                                                                         \
    _Pragma("unroll") for (int s_ = 0; s_ < 2; ++s_) {                         \
      __builtin_amdgcn_global_load_lds(                                        \
          (const __attribute__((address_space(1))) void*)(                     \
              aSrc + (size_t)((H) * 128 + s_ * 64) * K + (KT) * BKT),          \
          (__attribute__((address_space(3))) void*)(                           \
              &As[BUF][H][s_ * 64 + w * 8][0]),                                \
          16, 0, 0);                                                           \
    }                                                                          \
  } while (0)

#define STAGE_B(BUF, H, KT)                                                    \
  do {                                                                         \
    _Pragma("unroll") for (int s_ = 0; s_ < 2; ++s_) {                         \
      __builtin_amdgcn_global_load_lds(                                        \
          (const __attribute__((address_space(1))) void*)(                     \
              bSrc + (size_t)((H) * 128 + s_ * 64) * K + (KT) * BKT),          \
          (__attribute__((address_space(3))) void*)(                           \
              &Bs[BUF][H][s_ * 64 + w * 8][0]),                                \
          16, 0, 0);                                                           \
    }                                                                          \
  } while (0)

  // fragment reads: logical k-chunk c = ks*4+lk lives at phys chunk c^(r&7),
  // r&7 == lm&7 (row bases are multiples of 16).
#define RD_A(BUF, MH)                                                          \
  _Pragma("unroll") for (int mq = 0; mq < 4; ++mq)                             \
  _Pragma("unroll") for (int ks = 0; ks < 2; ++ks)                             \
      af[mq][ks] = *(const bf16x8*)&As[BUF][wm][(MH) * 64 + mq * 16 + lm]      \
                                      [((ks * 4 + lk) ^ (lm & 7)) * 8];

#define RD_B(BUF, NF0)                                                         \
  _Pragma("unroll") for (int nf = (NF0); nf < (NF0) + 2; ++nf)                 \
  _Pragma("unroll") for (int ks = 0; ks < 2; ++ks)                             \
      bf[nf][ks] =                                                             \
          *(const bf16x8*)&Bs[BUF][wn >> 1][(wn & 1) * 64 + nf * 16 + lm]      \
                              [((ks * 4 + lk) ^ (lm & 7)) * 8];

#define MFMA_Q(MH, NB)                                                         \
  _Pragma("unroll") for (int mq = 0; mq < 4; ++mq)                             \
  _Pragma("unroll") for (int nq = 0; nq < 2; ++nq)                             \
  _Pragma("unroll") for (int ks = 0; ks < 2; ++ks)                             \
      acc[(MH) * 4 + mq][(NB) + nq] =                                          \
          __builtin_amdgcn_mfma_f32_16x16x32_bf16(                             \
              af[mq][ks], bf[(NB) + nq][ks], acc[(MH) * 4 + mq][(NB) + nq],    \
              0, 0, 0);

  f32x4 acc[8][4] = {};
  bf16x8 af[4][2];
  bf16x8 bf[4][2];

  // prologue: tile0 -> buf0 (first 8 loads), tile1 -> buf1 (next 8).
  // vmcnt(8): tile0 landed, tile1's 8 loads in flight == steady-state
  // invariant at every ph8 exit.
  STAGE_A(0, 0, 0); STAGE_A(0, 1, 0);
  STAGE_B(0, 0, 0); STAGE_B(0, 1, 0);
  STAGE_B(1, 0, 1); STAGE_B(1, 1, 1);
  STAGE_A(1, 0, 1); STAGE_A(1, 1, 1);
  WAIT_VM8();
  FENCE(); BAR(); FENCE();

  const int NT = K / BKT;  // 64
  for (int i = 0; i < NT / 2; ++i) {
    const int kt2 = (2 * i + 2 < NT) ? (2 * i + 2) : (NT - 1);  // clamp tail
    const int kt3 = (2 * i + 3 < NT) ? (2 * i + 3) : (NT - 1);

    // ---- phase 1: read A-lo + B-lo (buf0); no staging
    RD_A(0, 0); RD_B(0, 0);
    FENCE(); BAR(); WAIT_LGKM0();
    __builtin_amdgcn_s_setprio(1); MFMA_Q(0, 0); __builtin_amdgcn_s_setprio(0);
    FENCE(); BAR();

    // ---- phase 2: read B-hi; no staging
    RD_B(0, 2);
    FENCE(); BAR(); WAIT_LGKM0();
    __builtin_amdgcn_s_setprio(1); MFMA_Q(0, 2); __builtin_amdgcn_s_setprio(0);
    FENCE(); BAR();

    // ---- phase 3: read A-hi; stage B(2i+2)->buf0 (B slots free after ph2)
    RD_A(0, 1);
    STAGE_B(0, 0, kt2); STAGE_B(0, 1, kt2);
    FENCE(); BAR(); WAIT_LGKM0();
    __builtin_amdgcn_s_setprio(1); MFMA_Q(1, 2); __builtin_amdgcn_s_setprio(0);
    FENCE(); BAR();

    // ---- phase 4: stage A(2i+2)->buf0 (A slots free after ph3);
    //      vmcnt(8) -> tile 2i+1 (staged prev ph7/ph8) landed
    STAGE_A(0, 0, kt2); STAGE_A(0, 1, kt2);
    FENCE(); BAR();
    __builtin_amdgcn_s_setprio(1); MFMA_Q(1, 0); __builtin_amdgcn_s_setprio(0);
    WAIT_VM8();
    FENCE(); BAR();

    // ---- phase 5: read A-lo + B-lo (buf1); no staging
    RD_A(1, 0); RD_B(1, 0);
    FENCE(); BAR(); WAIT_LGKM0();
    __builtin_amdgcn_s_setprio(1); MFMA_Q(0, 0); __builtin_amdgcn_s_setprio(0);
    FENCE(); BAR();

    // ---- phase 6: read B-hi; no staging
    RD_B(1, 2);
    FENCE(); BAR(); WAIT_LGKM0();
    __builtin_amdgcn_s_setprio(1); MFMA_Q(0, 2); __builtin_amdgcn_s_setprio(0);
    FENCE(); BAR();

    // ---- phase 7: read A-hi; stage B(2i+3)->buf1 (B slots free after ph6)
    RD_A(1, 1);
    STAGE_B(1, 0, kt3); STAGE_B(1, 1, kt3);
    FENCE(); BAR(); WAIT_LGKM0();
    __builtin_amdgcn_s_setprio(1); MFMA_Q(1, 2); __builtin_amdgcn_s_setprio(0);
    FENCE(); BAR();

    // ---- phase 8: stage A(2i+3)->buf1 (A slots free after ph7);
    //      vmcnt(8) -> tile 2i+2 (staged ph3/ph4) landed
    STAGE_A(1, 0, kt3); STAGE_A(1, 1, kt3);
    FENCE(); BAR();
    __builtin_amdgcn_s_setprio(1); MFMA_Q(1, 0); __builtin_amdgcn_s_setprio(0);
    WAIT_VM8();
    FENCE(); BAR();
  }

  float scale = (float)fmin(fmax(sum[0] * inv_cnt, 1e-5), 1000.0);

  // C/D layout (m89-verified): col = lane&15, row = (lane>>4)*4 + reg
#pragma unroll
  for (int nf = 0; nf < 4; ++nf) {
    const int col = n0 + wn * 64 + nf * 16 + lm;
    const float bv = bias[col];
#pragma unroll
    for (int mf = 0; mf < 8; ++mf) {
      const int row = m0 + wm * 128 + mf * 16 + lk * 4;
      float* op = out + (size_t)row * N + col;
#pragma unroll
      for (int r = 0; r < 4; ++r)
        op[(size_t)r * N] = acc[mf][nf][r] * scale + bv;
    }
  }
}

// ---------------------------------------------------------------- launch
extern "C" void kernel_launch(void* const* d_in, const int* in_sizes, int n_in,
                              void* d_out, int out_size, void* d_ws,
                              size_t ws_size, hipStream_t stream) {
  const float* x = (const float*)d_in[0];
  const float* w = (const float*)d_in[1];
  const float* bias = (const float*)d_in[2];
  float* out = (float*)d_out;

  const int DOUT = in_sizes[2];        // 4096
  const int DIN = in_sizes[1] / DOUT;  // 4096
  const int M = in_sizes[0] / DIN;     // 8192
  const int N = DOUT, K = DIN;

  char* ws = (char*)d_ws;
  double* sum = (double*)ws;                                   // 8 B
  ushort* xb = (ushort*)(ws + 256);                            // M*K*2 B
  ushort* qb = (ushort*)(ws + 256 + (size_t)M * K * 2);        // N*K*2 B

  const double inv_cnt = 1.0 / ((double)N * (double)K);

  hipMemsetAsync(d_ws, 0, 8, stream);

  const int wn4 = (N * K) / 4;
  const int wn8 = (N * K) / 8;
  absum_kernel<<<1024, 256, 0, stream>>>((const float4*)w, wn4, sum);
  quant_kernel<<<4096, 256, 0, stream>>>((const float4*)w, wn8, sum, inv_cnt,
                                         (u16x8*)qb);
  const int xn8 = (M * K) / 8;
  xcvt_kernel<<<8192, 256, 0, stream>>>((const float4*)x, xn8, (u16x8*)xb);

  const int nwg = (M >> 8) * (N >> 8);  // 32*16 = 512, divisible by 8
  gemm_kernel<<<dim3(nwg), 512, 0, stream>>>(xb, qb, bias, sum, out, M, N, K,
                                             inv_cnt);
}

// Round 4
// 548.782 us; speedup vs baseline: 1.1240x; 1.0698x over previous
//
#include <hip/hip_runtime.h>
#include <hip/hip_bf16.h>
#include <stdint.h>

// BitNet b1.58 linear: out[M,N] = x[M,K] @ (ternary(W)*scale)[N,K]^T + bias[N]
// M=8192, N=4096, K=4096.
//
// R5 -> R6: abandon the 1-block/CU 8-phase lockstep (measured 35% MfmaUtil;
// barrier-lockstep cannot overlap LDS reads with MFMA, and register budget
// forbids fragment double-buffering). Return to R2's proven mechanism --
// cross-block overlap (2+ blocks/CU, m114 implicit pipelining) -- at R5's
// better LDS-read:MFMA ratio (wave = 128x64 -> 24 ds_read_b128 per 64 MFMA):
//   - 256x128 tile, 4 waves (2M x 2N), single-buffered 48 KiB LDS
//   - 2 blocks/CU (VGPR-bound: ~240 regs/wave incl. 128 acc)
//   - 2 barriers per K-tile (plain __syncthreads; no inter-cluster barriers,
//     compiler schedules lgkmcnt fine-grained per m97 evidence)
//   - XOR chunk swizzle + bijective XCD swizzle + setprio on MFMA clusters
// Prepass fix: absum's serialized same-address f64 atomics (1024x) replaced
// by per-block partials + tiny final reduce; memset dispatch dropped.

typedef __bf16 bf16x8 __attribute__((ext_vector_type(8)));
typedef float f32x4 __attribute__((ext_vector_type(4)));
typedef unsigned short u16x8 __attribute__((ext_vector_type(8)));

__device__ __forceinline__ unsigned short f2bf_rne(float f) {
  union { float f; unsigned int u; } v; v.f = f;
  unsigned int u = v.u;
  u += 0x7FFFu + ((u >> 16) & 1u);
  return (unsigned short)(u >> 16);
}

// ---------------------------------------------------------------- reduction
__global__ void absum_part(const float4* __restrict__ w, int n4,
                           float* __restrict__ partial) {
  float s = 0.f;
  for (int i = blockIdx.x * blockDim.x + threadIdx.x; i < n4;
       i += gridDim.x * blockDim.x) {
    float4 v = w[i];
    s += fabsf(v.x) + fabsf(v.y) + fabsf(v.z) + fabsf(v.w);
  }
#pragma unroll
  for (int off = 32; off > 0; off >>= 1) s += __shfl_down(s, off);
  __shared__ float lds[4];
  if ((threadIdx.x & 63) == 0) lds[threadIdx.x >> 6] = s;
  __syncthreads();
  if (threadIdx.x == 0)
    partial[blockIdx.x] = lds[0] + lds[1] + lds[2] + lds[3];
}

__global__ void absum_final(const float* __restrict__ partial, int n,
                            double* __restrict__ out) {
  double s = 0.0;
  for (int i = threadIdx.x; i < n; i += blockDim.x) s += (double)partial[i];
#pragma unroll
  for (int off = 32; off > 0; off >>= 1) s += __shfl_down(s, off);
  __shared__ double lds[4];
  if ((threadIdx.x & 63) == 0) lds[threadIdx.x >> 6] = s;
  __syncthreads();
  if (threadIdx.x == 0) out[0] = lds[0] + lds[1] + lds[2] + lds[3];
}

// ---------------------------------------------------------------- quantize W
__global__ void quant_kernel(const float4* __restrict__ w, int n8,
                             const double* __restrict__ sum, double inv_cnt,
                             u16x8* __restrict__ q) {
  float scale = (float)fmin(fmax(sum[0] * inv_cnt, 1e-5), 1000.0);
  const float T = 2.0f / 3.0f;
  for (int i = blockIdx.x * blockDim.x + threadIdx.x; i < n8;
       i += gridDim.x * blockDim.x) {
    float4 a = w[2 * i], b = w[2 * i + 1];
    float f[8] = {a.x, a.y, a.z, a.w, b.x, b.y, b.z, b.w};
    u16x8 o;
#pragma unroll
    for (int j = 0; j < 8; ++j) {
      float n = f[j] / scale;
      o[j] = (n > T) ? 0x3F80u : ((n < -T) ? 0xBF80u : 0u);
    }
    q[i] = o;
  }
}

// ---------------------------------------------------------------- x -> bf16
__global__ void xcvt_kernel(const float4* __restrict__ x, int n8,
                            u16x8* __restrict__ xb) {
  for (int i = blockIdx.x * blockDim.x + threadIdx.x; i < n8;
       i += gridDim.x * blockDim.x) {
    float4 a = x[2 * i], b = x[2 * i + 1];
    float f[8] = {a.x, a.y, a.z, a.w, b.x, b.y, b.z, b.w};
    u16x8 o;
#pragma unroll
    for (int j = 0; j < 8; ++j) o[j] = f2bf_rne(f[j]);
    xb[i] = o;
  }
}

// ---------------------------------------------------------------- GEMM
// 256(M) x 128(N) tile, BK=64, 256 threads (4 waves: wm = w>>1, wn = w&1).
// Wave output 128x64 (acc[8][4] f32x4 = 128 regs). LDS single-buffered:
// As[256][64] (32 KiB) + Bs[128][64] (16 KiB) = 48 KiB -> 2 blocks/CU
// (VGPR-limited). Per K-tile: stage 12 gload_lds -> syncthreads (vmcnt0)
// -> 4 read+MFMA clusters (per-wave lgkm, no barriers) -> syncthreads.
// The stage/drain of one block overlaps the compute of the co-resident one.

#define BKT 64

__global__ __launch_bounds__(256, 2)
void gemm_kernel(const ushort* __restrict__ xb,   // [M,K] bf16 bits
                 const ushort* __restrict__ qb,   // [N,K] bf16 bits
                 const float* __restrict__ bias,  // [N]
                 const double* __restrict__ sum,
                 float* __restrict__ out,         // [M,N]
                 int M, int N, int K, double inv_cnt) {
  __shared__ __align__(16) ushort As[256][64];
  __shared__ __align__(16) ushort Bs[128][64];

  const int t = threadIdx.x;
  const int w = t >> 6;
  const int lane = t & 63;
  const int wm = w >> 1;  // 0..1, wave's 128-row slab
  const int wn = w & 1;   // 0..1, wave's 64-col slab
  const int lm = lane & 15;
  const int lk = lane >> 4;

  // bijective XCD swizzle (nwg = 1024, % 8 == 0)
  const int nbx = N >> 7;                 // 32
  const int cpx = gridDim.x >> 3;         // 128
  const int id = blockIdx.x;
  const int swz = (id & 7) * cpx + (id >> 3);
  const int bx = swz % nbx;
  const int by = swz / nbx;
  const int m0 = by << 8;   // 256-row tile
  const int n0 = bx << 7;   // 128-col tile

  // staging: one global_load_lds = 256 thr x 16 B = 4 KiB = 32 rows.
  // Per wave 8 rows (srow = lane>>3); LDS dest linear; XOR swizzle applied
  // on the GLOBAL source chunk: phys chunk (l&7) of row r holds logical
  // chunk (l&7)^(r&7).
  const int srow = lane >> 3;              // 0..7
  const int schunk = (lane & 7) ^ srow;    // pre-swizzled source chunk
  const ushort* aSrc = xb + (size_t)(m0 + w * 8 + srow) * K + schunk * 8;
  const ushort* bSrc = qb + (size_t)(n0 + w * 8 + srow) * K + schunk * 8;

  // fragment reads: logical k-chunk c = ks*4+lk lives at phys chunk c^(r&7),
  // r&7 == lm&7 (row bases are multiples of 16).
#define RD_A(MH)                                                               \
  _Pragma("unroll") for (int mq = 0; mq < 4; ++mq)                             \
  _Pragma("unroll") for (int ks = 0; ks < 2; ++ks)                             \
      af[mq][ks] = *(const bf16x8*)&As[wm * 128 + (MH) * 64 + mq * 16 + lm]    \
                                      [((ks * 4 + lk) ^ (lm & 7)) * 8];

#define RD_B(NF0)                                                              \
  _Pragma("unroll") for (int nf = (NF0); nf < (NF0) + 2; ++nf)                 \
  _Pragma("unroll") for (int ks = 0; ks < 2; ++ks)                             \
      bf[nf][ks] = *(const bf16x8*)&Bs[wn * 64 + nf * 16 + lm]                 \
                                      [((ks * 4 + lk) ^ (lm & 7)) * 8];

#define MFMA_Q(MH, NB)                                                         \
  _Pragma("unroll") for (int mq = 0; mq < 4; ++mq)                             \
  _Pragma("unroll") for (int nq = 0; nq < 2; ++nq)                             \
  _Pragma("unroll") for (int ks = 0; ks < 2; ++ks)                             \
      acc[(MH) * 4 + mq][(NB) + nq] =                                          \
          __builtin_amdgcn_mfma_f32_16x16x32_bf16(                             \
              af[mq][ks], bf[(NB) + nq][ks], acc[(MH) * 4 + mq][(NB) + nq],    \
              0, 0, 0);

  f32x4 acc[8][4] = {};
  bf16x8 af[4][2];
  bf16x8 bf[4][2];

  const int NT = K / BKT;  // 64
  for (int kt = 0; kt < NT; ++kt) {
    // ---- stage: A 8 loads (256 rows), B 4 loads (128 rows)
#pragma unroll
    for (int s = 0; s < 8; ++s)
      __builtin_amdgcn_global_load_lds(
          (const __attribute__((address_space(1))) void*)(
              aSrc + (size_t)s * 32 * K + kt * BKT),
          (__attribute__((address_space(3))) void*)(&As[s * 32 + w * 8][0]),
          16, 0, 0);
#pragma unroll
    for (int s = 0; s < 4; ++s)
      __builtin_amdgcn_global_load_lds(
          (const __attribute__((address_space(1))) void*)(
              bSrc + (size_t)s * 32 * K + kt * BKT),
          (__attribute__((address_space(3))) void*)(&Bs[s * 32 + w * 8][0]),
          16, 0, 0);
    __syncthreads();  // vmcnt(0) + lgkmcnt(0) + barrier

    // ---- cluster 1: A-lo x B01
    RD_A(0); RD_B(0);
    __builtin_amdgcn_s_setprio(1); MFMA_Q(0, 0); __builtin_amdgcn_s_setprio(0);
    // ---- cluster 2: A-lo x B23
    RD_B(2);
    __builtin_amdgcn_s_setprio(1); MFMA_Q(0, 2); __builtin_amdgcn_s_setprio(0);
    // ---- cluster 3: A-hi x B23
    RD_A(1);
    __builtin_amdgcn_s_setprio(1); MFMA_Q(1, 2); __builtin_amdgcn_s_setprio(0);
    // ---- cluster 4: A-hi x B01
    __builtin_amdgcn_s_setprio(1); MFMA_Q(1, 0); __builtin_amdgcn_s_setprio(0);

    __syncthreads();  // all reads of this tile done before next stage
  }

  float scale = (float)fmin(fmax(sum[0] * inv_cnt, 1e-5), 1000.0);

  // C/D layout (m89-verified): col = lane&15, row = (lane>>4)*4 + reg
#pragma unroll
  for (int nf = 0; nf < 4; ++nf) {
    const int col = n0 + wn * 64 + nf * 16 + lm;
    const float bv = bias[col];
#pragma unroll
    for (int mf = 0; mf < 8; ++mf) {
      const int row = m0 + wm * 128 + mf * 16 + lk * 4;
      float* op = out + (size_t)row * N + col;
#pragma unroll
      for (int r = 0; r < 4; ++r)
        op[(size_t)r * N] = acc[mf][nf][r] * scale + bv;
    }
  }
}

// ---------------------------------------------------------------- launch
extern "C" void kernel_launch(void* const* d_in, const int* in_sizes, int n_in,
                              void* d_out, int out_size, void* d_ws,
                              size_t ws_size, hipStream_t stream) {
  const float* x = (const float*)d_in[0];
  const float* w = (const float*)d_in[1];
  const float* bias = (const float*)d_in[2];
  float* out = (float*)d_out;

  const int DOUT = in_sizes[2];        // 4096
  const int DIN = in_sizes[1] / DOUT;  // 4096
  const int M = in_sizes[0] / DIN;     // 8192
  const int N = DOUT, K = DIN;

  char* ws = (char*)d_ws;
  double* sum = (double*)ws;                                    // 8 B
  float* partial = (float*)(ws + 256);                          // 1 KiB
  ushort* xb = (ushort*)(ws + 4096);                            // M*K*2 B
  ushort* qb = (ushort*)(ws + 4096 + (size_t)M * K * 2);        // N*K*2 B

  const double inv_cnt = 1.0 / ((double)N * (double)K);

  const int wn4 = (N * K) / 4;
  const int wn8 = (N * K) / 8;
  absum_part<<<256, 256, 0, stream>>>((const float4*)w, wn4, partial);
  absum_final<<<1, 256, 0, stream>>>(partial, 256, sum);
  quant_kernel<<<4096, 256, 0, stream>>>((const float4*)w, wn8, sum, inv_cnt,
                                         (u16x8*)qb);
  const int xn8 = (M * K) / 8;
  xcvt_kernel<<<8192, 256, 0, stream>>>((const float4*)x, xn8, (u16x8*)xb);

  const int nwg = (M >> 8) * (N >> 7);  // 32*32 = 1024, divisible by 8
  gemm_kernel<<<dim3(nwg), 256, 0, stream>>>(xb, qb, bias, sum, out, M, N, K,
                                             inv_cnt);
}